// Round 5
// baseline (166.626 us; speedup 1.0000x reference)
//
#include <hip/hip_runtime.h>

// Chamfer loss via 32x32x16 MFMA, two symmetric row-min passes.
// N=4, P1=P2=8192, D=3, K=1.
// d2 = |x|^2+|y|^2-2x.y == sum_{k<16} A[i][k]*B[j][k], fp16 hi/lo splits
// (products exact, fp32 MFMA accumulate; only split residual ~2^-22 dropped):
//   A row-style: [h0,h1,h2, l0,l1,l2, h0,h1 | h2, wh,wl, 1,1, l0,l1,l2]
//   B col-style: [-2h0..2, -2h0..2, -2l0,-2l1 | -2l2, 1,1, qh,ql, -2l0..2]
// K=16 exactly fits mfma_f32_32x32x16_f16 (no zero padding). Same-lane-map
// loading (16B at [pt][ (lane>>5)*8 ]) for both A and B makes the result the
// slot-wise dot product regardless of the HW k order (k-permutation
// invariance; empirically validated for the 16x16x32 analog, rounds 1-4).
// C/D layout (HW-verified): col = lane&31, row = (r&3)+8*(r>>2)+4*(lane>>5).
//
// Work decomposition: flat unit list, balanced from lens at runtime.
//   unit = (pass, b, 64-row tile tau, 1024-col chunk ch) over VALID rows/cols:
//     pass0: rows = pred (all 128 tiles), cols = targ[0..L) -> chunks < NC_b
//     pass1: rows = targ[0..ceil(L/64)*64), cols = pred (8 chunks)
//   uid = XCD-swizzled flat wave id; every executing wave runs ~16 equal steps.
// Inner step (wave-autonomous, no LDS/barriers): 2 prefetched B-frag loads
// (depth-2, 3 buffers) + 4 MFMA + 32 min3. Invalid cols get a mask fragment
// (qh slot = 65504 -> d2 = 65504, never wins). Row-min closes per wave with
// 5 shfl_xor per acc reg, once per unit.

typedef _Float16 f16;
typedef _Float16 half8 __attribute__((ext_vector_type(8)));
typedef float f32x16 __attribute__((ext_vector_type(16)));

constexpr int N = 4;
constexpr int P = 8192;
constexpr float BIGV = 1e30f;

__global__ __launch_bounds__(256) void chamfer_prep(
    const float* __restrict__ pred, const float* __restrict__ targ,
    f16* __restrict__ rowP, f16* __restrict__ colP,
    f16* __restrict__ rowT, f16* __restrict__ colT)
{
    const int idx = blockIdx.x * 256 + threadIdx.x;    // [0, N*P)
    const f16 one = (f16)1.0f;
    #pragma unroll
    for (int which = 0; which < 2; ++which) {
        const float* s = (which ? targ : pred) + (size_t)idx * 3;
        half8* rdst = (half8*)((which ? rowT : rowP) + (size_t)idx * 16);
        half8* cdst = (half8*)((which ? colT : colP) + (size_t)idx * 16);
        const float x0 = s[0], x1 = s[1], x2 = s[2];
        const float w = fmaf(x0, x0, fmaf(x1, x1, x2 * x2));
        const f16 h0 = (f16)x0, h1 = (f16)x1, h2 = (f16)x2;
        const f16 l0 = (f16)(x0 - (float)h0), l1 = (f16)(x1 - (float)h1), l2 = (f16)(x2 - (float)h2);
        const f16 wh = (f16)w, wl = (f16)(w - (float)wh);
        half8 r0 = {h0, h1, h2, l0, l1, l2, h0, h1};
        half8 r1 = {h2, wh, wl, one, one, l0, l1, l2};
        rdst[0] = r0; rdst[1] = r1;
        const f16 n0 = (f16)(-2.0f * (float)h0), n1 = (f16)(-2.0f * (float)h1), n2 = (f16)(-2.0f * (float)h2);
        const f16 u0 = (f16)(-2.0f * (float)l0), u1 = (f16)(-2.0f * (float)l1), u2 = (f16)(-2.0f * (float)l2);
        half8 c0v = {n0, n1, n2, n0, n1, n2, u0, u1};
        half8 c1v = {u2, one, one, wh, wl, u0, u1, u2};
        cdst[0] = c0v; cdst[1] = c1v;
    }
}

__global__ __launch_bounds__(256) void chamfer_pass(
    const f16* __restrict__ rowP, const f16* __restrict__ colP,
    const f16* __restrict__ rowT, const f16* __restrict__ colT,
    const int* __restrict__ lens, float* __restrict__ part)
{
    // XCD-chunked bijective swizzle (2048 blocks, 2048%8==0): XCD x hosts
    // uid range [x*1024, (x+1)*1024): consecutive units share B panels.
    const int H   = blockIdx.x;
    const int Lid = (H & 7) * 256 + (H >> 3);
    const int tid  = threadIdx.x;
    const int w    = tid >> 6;
    const int lane = tid & 63;
    const int uid  = Lid * 4 + w;
    const int lc   = lane & 31;               // point-in-tile (A row / B col)
    const int kh   = lane >> 5;               // k-half
    const int kh8  = kh * 8;

    // ---- decode uid -> (pass, b, tau, ch) via runtime prefix over 8 groups
    int Ls[4], CT[4], NC[4];
    #pragma unroll
    for (int i = 0; i < 4; ++i) {
        Ls[i] = lens[i];
        CT[i] = (Ls[i] + 63) >> 6;            // valid 64-tiles
        NC[i] = (CT[i] + 15) >> 4;            // pass0 col chunks (<=8)
    }
    int pass = -1, b = 0, local = uid;
    #pragma unroll
    for (int i = 0; i < 8; ++i) {
        const int sz = (i < 4) ? 128 * NC[i] : CT[i - 4] * 8;
        if (pass < 0) {
            if (local < sz) { pass = i >> 2; b = i & 3; }
            else local -= sz;
        }
    }
    if (pass < 0) return;                     // uid >= total units

    const int L = Ls[b];
    int ch, tau;
    if (pass == 0) { ch = local >> 7; tau = local & 127; }   // chunk-major
    else           { ch = local / CT[b]; tau = local - ch * CT[b]; }

    const int row0   = tau * 64;
    const int cstart = ch * 1024;
    const int cend0  = CT[b] * 64;
    const int cend   = pass ? (cstart + 1024)
                            : ((cstart + 1024 < cend0) ? cstart + 1024 : cend0);
    const int colLim = pass ? P : L;

    const f16* ab = (pass ? rowT : rowP) + (size_t)b * (P * 16);
    const f16* bb = (pass ? colP : colT) + (size_t)b * (P * 16);
    float* wrow = part + (((size_t)pass * N + b) * 8 + ch) * P + row0;

    // persistent A fragments (2 row tiles of 32)
    const half8 afr0 = *(const half8*)(ab + (size_t)(row0 + lc) * 16 + kh8);
    const half8 afr1 = *(const half8*)(ab + (size_t)(row0 + 32 + lc) * 16 + kh8);

    // mask fragment: only qh slot (global slot 11 = half 1, elem 3) nonzero
    half8 mfr = {0, 0, 0, 0, 0, 0, 0, 0};
    if (kh) mfr[3] = (f16)65504.0f;           // d2(masked col) = 65504, never wins

    float acc0[16], acc1[16];
    #pragma unroll
    for (int r = 0; r < 16; ++r) { acc0[r] = BIGV; acc1[r] = BIGV; }

    const f32x16 zz = {0.f,0.f,0.f,0.f, 0.f,0.f,0.f,0.f,
                       0.f,0.f,0.f,0.f, 0.f,0.f,0.f,0.f};

    auto LOADF = [&](half8* dst, int cb) {
        if (cb + 64 <= colLim) {              // wave-uniform fast path
            dst[0] = *(const half8*)(bb + (size_t)(cb + lc) * 16 + kh8);
            dst[1] = *(const half8*)(bb + (size_t)(cb + 32 + lc) * 16 + kh8);
        } else {                              // boundary / overshoot prefetch
            #pragma unroll
            for (int ct = 0; ct < 2; ++ct) {
                const int col = cb + ct * 32 + lc;
                dst[ct] = (col < colLim)
                    ? *(const half8*)(bb + (size_t)col * 16 + kh8) : mfr;
            }
        }
    };
    auto COMP = [&](const half8* cur) {
        const f32x16 d0 = __builtin_amdgcn_mfma_f32_32x32x16_f16(afr0, cur[0], zz, 0, 0, 0);
        const f32x16 d1 = __builtin_amdgcn_mfma_f32_32x32x16_f16(afr0, cur[1], zz, 0, 0, 0);
        #pragma unroll
        for (int r = 0; r < 16; ++r)
            acc0[r] = fminf(fminf(acc0[r], d0[r]), d1[r]);     // -> v_min3_f32
        const f32x16 e0 = __builtin_amdgcn_mfma_f32_32x32x16_f16(afr1, cur[0], zz, 0, 0, 0);
        const f32x16 e1 = __builtin_amdgcn_mfma_f32_32x32x16_f16(afr1, cur[1], zz, 0, 0, 0);
        #pragma unroll
        for (int r = 0; r < 16; ++r)
            acc1[r] = fminf(fminf(acc1[r], e0[r]), e1[r]);
    };

    half8 B0[2], B1[2], B2[2];
    int njs = (cend - cstart + 63) >> 6;
    int c = cstart;
    LOADF(B0, c);
    LOADF(B1, c + 64);
    while (njs >= 3) {                        // depth-2 prefetch, 3x unrolled
        LOADF(B2, c + 128);
        COMP(B0);
        LOADF(B0, c + 192);
        COMP(B1);
        LOADF(B1, c + 256);
        COMP(B2);
        c += 192; njs -= 3;
    }
    if (njs == 2) { COMP(B0); COMP(B1); }
    else if (njs == 1) { COMP(B0); }

    // wave-local row-min close: min over 32 col-lanes, scatter-store 64 rows.
    #pragma unroll
    for (int rt = 0; rt < 2; ++rt) {
        #pragma unroll
        for (int r = 0; r < 16; ++r) {
            float v = rt ? acc1[r] : acc0[r];
            v = fminf(v, __shfl_xor(v, 1, 64));
            v = fminf(v, __shfl_xor(v, 2, 64));
            v = fminf(v, __shfl_xor(v, 4, 64));
            v = fminf(v, __shfl_xor(v, 8, 64));
            v = fminf(v, __shfl_xor(v, 16, 64));
            if (lc == 0)
                wrow[rt * 32 + (r & 3) + 8 * (r >> 2) + 4 * kh] = v;
        }
    }
}

__global__ __launch_bounds__(256) void chamfer_reduce(
    const float* __restrict__ part, const int* __restrict__ lens,
    float* __restrict__ out)
{
    const int item = blockIdx.x * 256 + threadIdx.x;   // 2*N*P = 65536
    const int dir = item >> 15;
    const int b   = (item >> 13) & (N - 1);
    const int p   = item & (P - 1);
    const int L   = lens[b];

    float c = 0.f;
    if (dir == 0) {        // pred->targ: min over NC_b chunk slots
        const int NCb = (((L + 63) >> 6) + 15) >> 4;
        const float* base = part + ((size_t)b * 8) * P + p;
        float v = base[0];
        for (int s = 1; s < NCb; ++s) v = fminf(v, base[(size_t)s * P]);
        c = fmaxf(v, 0.f) * (1.0f / ((float)P * (float)N));
    } else if (p < L) {    // targ->pred: min over 8 chunk slots
        const float* base = part + (((size_t)N + b) * 8) * P + p;
        float v = base[0];
        #pragma unroll
        for (int s = 1; s < 8; ++s) v = fminf(v, base[(size_t)s * P]);
        c = fmaxf(v, 0.f) / ((float)L * (float)N);
    }
    #pragma unroll
    for (int off = 32; off; off >>= 1) c += __shfl_down(c, off, 64);
    __shared__ float acc[4];
    if ((threadIdx.x & 63) == 0) acc[threadIdx.x >> 6] = c;
    __syncthreads();
    if (threadIdx.x == 0) atomicAdd(out, acc[0] + acc[1] + acc[2] + acc[3]);
}

extern "C" void kernel_launch(void* const* d_in, const int* in_sizes, int n_in,
                              void* d_out, int out_size, void* d_ws, size_t ws_size,
                              hipStream_t stream)
{
    const float* pred = (const float*)d_in[0];
    const float* targ = (const float*)d_in[1];
    const int*   lens = (const int*)d_in[2];
    float* out = (float*)d_out;
    char*  ws  = (char*)d_ws;

    // ws: rowP | colP | rowT | colT (1MB each) | part 2*N*8*P floats (2MB)
    const size_t packb = (size_t)N * P * 16 * sizeof(f16);
    f16*   rowP = (f16*)ws;
    f16*   colP = (f16*)(ws + packb);
    f16*   rowT = (f16*)(ws + 2 * packb);
    f16*   colT = (f16*)(ws + 3 * packb);
    float* part = (float*)(ws + 4 * packb);

    hipMemsetAsync(out, 0, out_size * sizeof(float), stream);
    chamfer_prep<<<(N * P) / 256, 256, 0, stream>>>(pred, targ, rowP, colP, rowT, colT);
    chamfer_pass<<<2048, 256, 0, stream>>>(rowP, colP, rowT, colT, lens, part);
    chamfer_reduce<<<(2 * N * P) / 256, 256, 0, stream>>>(part, lens, out);
}